// Round 3
// baseline (934.462 us; speedup 1.0000x reference)
//
#include <hip/hip_runtime.h>
#include <hip/hip_bf16.h>

typedef unsigned short u16;
typedef unsigned int u32;

__device__ __forceinline__ float bf2f(u16 u) { return __uint_as_float(((u32)u) << 16); }
__device__ __forceinline__ float bl(u32 u) { return __uint_as_float(u << 16); }
__device__ __forceinline__ float bh(u32 u) { return __uint_as_float(u & 0xffff0000u); }
__device__ __forceinline__ u16 f2bf(float f) {
    u32 u = __float_as_uint(f);
    u += 0x7fffu + ((u >> 16) & 1u);   // round-to-nearest-even
    return (u16)(u >> 16);
}
__device__ __forceinline__ void unp8(uint4 r, float* o) {
    o[0] = bl(r.x); o[1] = bh(r.x); o[2] = bl(r.y); o[3] = bh(r.y);
    o[4] = bl(r.z); o[5] = bh(r.z); o[6] = bl(r.w); o[7] = bh(r.w);
}
__device__ __forceinline__ float lrelu(float x) { return x > 0.f ? x : 0.2f * x; }
__device__ __forceinline__ int clampi(int v, int lo, int hi) {
    return v < lo ? lo : (v > hi ? hi : v);
}
// flag-aware external loads: f32 != 0 -> buffer holds float32, else bf16
__device__ __forceinline__ float load1(const void* base, int idx, int f32) {
    return f32 ? ((const float*)base)[idx] : bf2f(((const u16*)base)[idx]);
}
__device__ __forceinline__ void load8(const void* base, int idx, int f32, float* o) {
    if (f32) {
        const float4* p = (const float4*)((const float*)base + idx);
        float4 a = p[0], b = p[1];
        o[0] = a.x; o[1] = a.y; o[2] = a.z; o[3] = a.w;
        o[4] = b.x; o[5] = b.y; o[6] = b.z; o[7] = b.w;
    } else {
        uint4 r = *(const uint4*)((const u16*)base + idx);
        unp8(r, o);
    }
}

// ---------------- dtype detector: sample first 512 u16 of x ------------------------------
// bf16 data: ~all u16 exponent fields in [0x60,0x8F]. fp32 data: only high halves (~59%).
__global__ void k_detect(const u32* __restrict__ xw, int* __restrict__ flag) {
    int lane = threadIdx.x & 63;
    int cnt = 0;
    #pragma unroll
    for (int j = 0; j < 4; j++) {
        u32 w = xw[lane * 4 + j];
        int e0 = (int)((w >> 7) & 0xffu);
        int e1 = (int)((w >> 23) & 0xffu);
        cnt += (e0 >= 0x60 && e0 <= 0x8f);
        cnt += (e1 >= 0x60 && e1 <= 0x8f);
    }
    #pragma unroll
    for (int off = 32; off > 0; off >>= 1) cnt += __shfl_xor(cnt, off);
    if (lane == 0) *flag = (cnt < 480) ? 1 : 0;   // 512 samples: bf16 ~510, fp32 ~300
}

// ---------------- constants: C1[h] = sum_c We1[h*32+c]*ae1[h*32+c]; C2 = sum We2*ae2 ----
__global__ void k_consts(const void* We1, const void* ae1, const void* We2, const void* ae2,
                         const int* __restrict__ flag, float* __restrict__ consts) {
    int f = *flag;
    int t = threadIdx.x;
    if (t < 4) {
        float s = 0.f;
        for (int c = 0; c < 32; c++) s += load1(We1, t * 32 + c, f) * load1(ae1, t * 32 + c, f);
        consts[t] = s;
    } else if (t == 4) {
        float s = 0.f;
        for (int c = 0; c < 64; c++) s += load1(We2, c, f) * load1(ae2, c, f);
        consts[4] = s;
    }
}

// ---------------- GEMM: Y[nrows,NC] = X[nrows,128] @ W[128,NC], flag-aware in, bf16 out --
template <int NC, int RPT>
__global__ __launch_bounds__(256) void k_gemm(const void* X, const void* Wg,
                                              const int* __restrict__ flag,
                                              int fXconst,   // -1: use *flag, else forced
                                              u16* __restrict__ Y, int nrows) {
    constexpr int K = 128;
    constexpr int CG = NC / 4;   // column groups of 4
    __shared__ float Ws[K * NC];
    __shared__ float Xs[32 * K];

    const int fW = *flag;
    const int fX = (fXconst < 0) ? fW : fXconst;

    // stage W once
    for (int i = threadIdx.x * 8; i < K * NC; i += 256 * 8) {
        float v[8]; load8(Wg, i, fW, v);
        #pragma unroll
        for (int j = 0; j < 8; j++) Ws[i + j] = v[j];
    }

    const int cg = threadIdx.x % CG;
    const int rg = threadIdx.x / CG;
    const int rb = rg * RPT;

    for (int tile = blockIdx.x * 32; tile < nrows; tile += gridDim.x * 32) {
        __syncthreads();
        for (int i = threadIdx.x * 8; i < 32 * K; i += 256 * 8) {
            int r = i >> 7;
            int gr = tile + r;
            float v[8];
            if (gr < nrows) {
                load8(X, gr * K + (i & 127), fX, v);
            } else {
                #pragma unroll
                for (int j = 0; j < 8; j++) v[j] = 0.f;
            }
            #pragma unroll
            for (int j = 0; j < 8; j++) Xs[i + j] = v[j];
        }
        __syncthreads();

        float acc[RPT][4];
        #pragma unroll
        for (int j = 0; j < RPT; j++)
            #pragma unroll
            for (int c = 0; c < 4; c++) acc[j][c] = 0.f;

        for (int k = 0; k < K; k += 4) {
            float4 w0 = *(float4*)&Ws[(k + 0) * NC + cg * 4];
            float4 w1 = *(float4*)&Ws[(k + 1) * NC + cg * 4];
            float4 w2 = *(float4*)&Ws[(k + 2) * NC + cg * 4];
            float4 w3 = *(float4*)&Ws[(k + 3) * NC + cg * 4];
            #pragma unroll
            for (int j = 0; j < RPT; j++) {
                float4 xv = *(float4*)&Xs[(rb + j) * K + k];
                acc[j][0] += xv.x * w0.x + xv.y * w1.x + xv.z * w2.x + xv.w * w3.x;
                acc[j][1] += xv.x * w0.y + xv.y * w1.y + xv.z * w2.y + xv.w * w3.y;
                acc[j][2] += xv.x * w0.z + xv.y * w1.z + xv.z * w2.z + xv.w * w3.z;
                acc[j][3] += xv.x * w0.w + xv.y * w1.w + xv.z * w2.w + xv.w * w3.w;
            }
        }
        #pragma unroll
        for (int j = 0; j < RPT; j++) {
            int gr = tile + rb + j;
            if (gr < nrows) {
                ushort4 o;
                o.x = f2bf(acc[j][0]); o.y = f2bf(acc[j][1]);
                o.z = f2bf(acc[j][2]); o.w = f2bf(acc[j][3]);
                *(ushort4*)&Y[gr * NC + cg * 4] = o;
            }
        }
    }
}

// ---------------- attention coefficients (layer1: 4 heads x 32ch); h internal bf16 ------
__global__ void k_coef1(const u16* __restrict__ h, const void* as_, const void* ad_,
                        const int* __restrict__ flag, float* __restrict__ asrc,
                        float* __restrict__ adst, int n) {
    int f = *flag;
    int i = blockIdx.x * 256 + threadIdx.x;
    if (i >= n * 4) return;
    int node = i >> 2, hd = i & 3;
    const u16* hp = h + node * 128 + hd * 32;
    float s1 = 0.f, s2 = 0.f;
    #pragma unroll
    for (int c = 0; c < 32; c += 8) {
        uint4 hv = *(const uint4*)&hp[c];
        float hf[8], af[8], df[8];
        unp8(hv, hf);
        load8(as_, hd * 32 + c, f, af);
        load8(ad_, hd * 32 + c, f, df);
        #pragma unroll
        for (int j = 0; j < 8; j++) { s1 += hf[j] * af[j]; s2 += hf[j] * df[j]; }
    }
    asrc[i] = s1; adst[i] = s2;
}

// ---------------- attention coefficients (layer2: 1 head x 64ch) -----------------------
__global__ void k_coef2(const u16* __restrict__ h, const void* as_, const void* ad_,
                        const int* __restrict__ flag, float* __restrict__ asrc,
                        float* __restrict__ adst, int n) {
    int f = *flag;
    int i = blockIdx.x * 256 + threadIdx.x;
    if (i >= n) return;
    const u16* hp = h + i * 64;
    float s1 = 0.f, s2 = 0.f;
    #pragma unroll
    for (int c = 0; c < 64; c += 8) {
        uint4 hv = *(const uint4*)&hp[c];
        float hf[8], af[8], df[8];
        unp8(hv, hf);
        load8(as_, c, f, af);
        load8(ad_, c, f, df);
        #pragma unroll
        for (int j = 0; j < 8; j++) { s1 += hf[j] * af[j]; s2 += hf[j] * df[j]; }
    }
    asrc[i] = s1; adst[i] = s2;
}

// ---------------- CSR build --------------------------------------------------------------
__global__ void k_count(const int* __restrict__ dst, int* __restrict__ cnt, int E, int n) {
    int e = blockIdx.x * 256 + threadIdx.x;
    if (e < E) atomicAdd(&cnt[clampi(dst[e], 0, n - 1)], 1);
}
__global__ void k_scan1(const int* __restrict__ cnt, int* __restrict__ part,
                        int* __restrict__ bsum, int n) {
    __shared__ int buf[256];
    int i = blockIdx.x * 256 + threadIdx.x;
    int v = (i < n) ? cnt[i] : 0;
    buf[threadIdx.x] = v;
    __syncthreads();
    for (int off = 1; off < 256; off <<= 1) {
        int t = (threadIdx.x >= off) ? buf[threadIdx.x - off] : 0;
        __syncthreads();
        buf[threadIdx.x] += t;
        __syncthreads();
    }
    if (i < n) part[i] = buf[threadIdx.x];
    if (threadIdx.x == 255) bsum[blockIdx.x] = buf[255];
}
__global__ void k_scan2(int* __restrict__ bsum, int nb) {
    __shared__ int buf[256];
    int t = threadIdx.x;
    int v = (t < nb) ? bsum[t] : 0;
    buf[t] = v;
    __syncthreads();
    for (int off = 1; off < 256; off <<= 1) {
        int tt = (t >= off) ? buf[t - off] : 0;
        __syncthreads();
        buf[t] += tt;
        __syncthreads();
    }
    if (t < nb) bsum[t] = buf[t] - v;   // exclusive
}
__global__ void k_scan3(int* __restrict__ roff, const int* __restrict__ bsum, int n) {
    int i = blockIdx.x * 256 + threadIdx.x;
    if (i > n) return;
    if (i == 0) { roff[0] = 0; return; }
    roff[i] += bsum[(i - 1) >> 8];
}
__global__ void k_copy(const int* __restrict__ roff, int* __restrict__ rpos, int n) {
    int i = blockIdx.x * 256 + threadIdx.x;
    if (i < n) rpos[i] = roff[i];
}
__global__ void k_scatter(const int* __restrict__ dst, int* __restrict__ rpos,
                          int* __restrict__ eids, int E, int n) {
    int e = blockIdx.x * 256 + threadIdx.x;
    if (e < E) {
        int p = atomicAdd(&rpos[clampi(dst[e], 0, n - 1)], 1);
        if (p >= 0 && p < E) eids[p] = e;
    }
}

// ---------------- fused per-dst softmax + aggregation, layer 1 (4 heads x 32) -----------
__global__ __launch_bounds__(256) void k_gat1(
    const u16* __restrict__ h, const float* __restrict__ asrc, const float* __restrict__ adst,
    const void* eattr, const int* __restrict__ srcs,
    const int* __restrict__ roff, const int* __restrict__ eids,
    const int* __restrict__ flag, const float* __restrict__ consts, const void* bias,
    u16* __restrict__ out, int n, int E) {
    int f = *flag;
    int gtid = blockIdx.x * 256 + threadIdx.x;
    int wv = gtid >> 6, lane = gtid & 63;
    int nw = (gridDim.x * 256) >> 6;
    const float c0 = consts[0], c1 = consts[1], c2 = consts[2], c3 = consts[3];
    const int hsel = lane >> 5;   // 0 or 1
    const float biasA = load1(bias, lane, f);
    const float biasB = load1(bias, 64 + lane, f);

    for (int d = wv; d < n; d += nw) {
        int s0 = clampi(roff[d], 0, E);
        int s1 = clampi(roff[d + 1], s0, E);
        float4 adv = *(const float4*)&adst[d * 4];
        float ad0 = adv.x, ad1 = adv.y, ad2 = adv.z, ad3 = adv.w;

        // pass 1: per-head max
        float m0 = -1e30f, m1 = -1e30f, m2 = -1e30f, m3 = -1e30f;
        for (int idx = s0 + lane; idx < s1; idx += 64) {
            int e = clampi(eids[idx], 0, E - 1);
            int s = clampi(srcs[e], 0, n - 1);
            float ea = load1(eattr, e, f);
            float4 av = *(const float4*)&asrc[s * 4];
            m0 = fmaxf(m0, lrelu(av.x + ad0 + ea * c0));
            m1 = fmaxf(m1, lrelu(av.y + ad1 + ea * c1));
            m2 = fmaxf(m2, lrelu(av.z + ad2 + ea * c2));
            m3 = fmaxf(m3, lrelu(av.w + ad3 + ea * c3));
        }
        #pragma unroll
        for (int off = 32; off > 0; off >>= 1) {
            m0 = fmaxf(m0, __shfl_xor(m0, off));
            m1 = fmaxf(m1, __shfl_xor(m1, off));
            m2 = fmaxf(m2, __shfl_xor(m2, off));
            m3 = fmaxf(m3, __shfl_xor(m3, off));
        }
        // pass 2: denominators
        float d0 = 0.f, d1 = 0.f, d2 = 0.f, d3 = 0.f;
        for (int idx = s0 + lane; idx < s1; idx += 64) {
            int e = clampi(eids[idx], 0, E - 1);
            int s = clampi(srcs[e], 0, n - 1);
            float ea = load1(eattr, e, f);
            float4 av = *(const float4*)&asrc[s * 4];
            d0 += expf(lrelu(av.x + ad0 + ea * c0) - m0);
            d1 += expf(lrelu(av.y + ad1 + ea * c1) - m1);
            d2 += expf(lrelu(av.z + ad2 + ea * c2) - m2);
            d3 += expf(lrelu(av.w + ad3 + ea * c3) - m3);
        }
        #pragma unroll
        for (int off = 32; off > 0; off >>= 1) {
            d0 += __shfl_xor(d0, off); d1 += __shfl_xor(d1, off);
            d2 += __shfl_xor(d2, off); d3 += __shfl_xor(d3, off);
        }
        float i0 = 1.f / (d0 + 1e-16f), i1 = 1.f / (d1 + 1e-16f);
        float i2 = 1.f / (d2 + 1e-16f), i3 = 1.f / (d3 + 1e-16f);

        // per-lane head selection: channel lane -> head hsel, channel lane+64 -> head 2+hsel
        float mA = hsel ? m1 : m0, mB = hsel ? m3 : m2;
        float iA = hsel ? i1 : i0, iB = hsel ? i3 : i2;
        float cA = hsel ? c1 : c0, cB = hsel ? c3 : c2;
        float aA = hsel ? ad1 : ad0, aB = hsel ? ad3 : ad2;

        // pass 3: weighted aggregation (all lanes walk all edges together)
        float accA = 0.f, accB = 0.f;
        for (int idx = s0; idx < s1; idx++) {
            int e = clampi(eids[idx], 0, E - 1);
            int s = clampi(srcs[e], 0, n - 1);
            float ea = load1(eattr, e, f);
            float4 av = *(const float4*)&asrc[s * 4];
            float alA = lrelu((hsel ? av.y : av.x) + aA + ea * cA);
            float alB = lrelu((hsel ? av.w : av.z) + aB + ea * cB);
            float wA = expf(alA - mA) * iA;
            float wB = expf(alB - mB) * iB;
            accA += wA * bf2f(h[s * 128 + lane]);
            accB += wB * bf2f(h[s * 128 + 64 + lane]);
        }
        out[d * 128 + lane]      = f2bf(fmaxf(accA + biasA, 0.f));   // fused ReLU
        out[d * 128 + 64 + lane] = f2bf(fmaxf(accB + biasB, 0.f));
    }
}

// ---------------- fused per-dst softmax + aggregation, layer 2 (1 head x 64) ------------
__global__ __launch_bounds__(256) void k_gat2(
    const u16* __restrict__ h, const float* __restrict__ asrc, const float* __restrict__ adst,
    const void* eattr, const int* __restrict__ srcs,
    const int* __restrict__ roff, const int* __restrict__ eids,
    const int* __restrict__ flag, const float* __restrict__ consts, const void* bias,
    u16* __restrict__ out, int n, int E) {
    int f = *flag;
    int gtid = blockIdx.x * 256 + threadIdx.x;
    int wv = gtid >> 6, lane = gtid & 63;
    int nw = (gridDim.x * 256) >> 6;
    const float C = consts[4];
    const float biasL = load1(bias, lane, f);

    for (int d = wv; d < n; d += nw) {
        int s0 = clampi(roff[d], 0, E);
        int s1 = clampi(roff[d + 1], s0, E);
        float ad = adst[d];
        float m = -1e30f;
        for (int idx = s0 + lane; idx < s1; idx += 64) {
            int e = clampi(eids[idx], 0, E - 1);
            int s = clampi(srcs[e], 0, n - 1);
            float ea = load1(eattr, e, f);
            m = fmaxf(m, lrelu(asrc[s] + ad + ea * C));
        }
        #pragma unroll
        for (int off = 32; off > 0; off >>= 1) m = fmaxf(m, __shfl_xor(m, off));
        float den = 0.f;
        for (int idx = s0 + lane; idx < s1; idx += 64) {
            int e = clampi(eids[idx], 0, E - 1);
            int s = clampi(srcs[e], 0, n - 1);
            float ea = load1(eattr, e, f);
            den += expf(lrelu(asrc[s] + ad + ea * C) - m);
        }
        #pragma unroll
        for (int off = 32; off > 0; off >>= 1) den += __shfl_xor(den, off);
        float inv = 1.f / (den + 1e-16f);

        float acc = 0.f;
        for (int idx = s0; idx < s1; idx++) {
            int e = clampi(eids[idx], 0, E - 1);
            int s = clampi(srcs[e], 0, n - 1);
            float ea = load1(eattr, e, f);
            float al = lrelu(asrc[s] + ad + ea * C);
            float w = expf(al - m) * inv;
            acc += w * bf2f(h[s * 64 + lane]);
        }
        out[d * 64 + lane] = f2bf(acc + biasL);
    }
}

// ---------------- pooling (batch values in [0,G)) ---------------------------------------
__global__ void k_pool(const u16* __restrict__ agg2, const int* __restrict__ batch,
                       float* __restrict__ pool, float* __restrict__ cnt, int n, int G) {
    int t = blockIdx.x * 256 + threadIdx.x;
    int nb8 = (n + 7) / 8;
    if (t >= nb8 * 64) return;
    int base = (t >> 6) * 8;
    int c = t & 63;
    int end = min(base + 8, n);
    float acc = 0.f, cacc = 0.f;
    int curg = clampi(batch[base], 0, G - 1);
    for (int j = base; j < end; j++) {
        int g = clampi(batch[j], 0, G - 1);
        if (g != curg) {
            atomicAdd(&pool[curg * 64 + c], acc);
            if (c == 0) atomicAdd(&cnt[curg], cacc);
            acc = 0.f; cacc = 0.f; curg = g;
        }
        acc += bf2f(agg2[j * 64 + c]);
        cacc += 1.f;
    }
    atomicAdd(&pool[curg * 64 + c], acc);
    if (c == 0) atomicAdd(&cnt[curg], cacc);
}

__global__ void k_head(const float* __restrict__ pool, const float* __restrict__ cnt,
                       const void* Wp, const void* bp, const int* __restrict__ flag,
                       void* out, int G) {
    int f = *flag;
    int g = threadIdx.x;
    if (g >= G) return;
    float s = 0.f;
    for (int c = 0; c < 64; c++) s += pool[g * 64 + c] * load1(Wp, c, f);
    float cv = cnt[g];
    if (!(cv > 0.f)) cv = 1.f;
    float r = s / cv + load1(bp, 0, f);
    if (f) ((float*)out)[g] = r;
    else   ((u16*)out)[g] = f2bf(r);
}

// ---------------- launch ----------------------------------------------------------------
extern "C" void kernel_launch(void* const* d_in, const int* in_sizes, int n_in,
                              void* d_out, int out_size, void* d_ws, size_t ws_size,
                              hipStream_t stream) {
    const void* x    = d_in[0];
    const int* ei    = (const int*)d_in[1];
    const void* eattr = d_in[2];
    const int* batch = (const int*)d_in[3];
    const void* W1   = d_in[4];
    const void* as1  = d_in[5];
    const void* ad1  = d_in[6];
    const void* We1  = d_in[7];
    const void* ae1  = d_in[8];
    const void* b1   = d_in[9];
    const void* W2   = d_in[10];
    const void* as2  = d_in[11];
    const void* ad2  = d_in[12];
    const void* We2  = d_in[13];
    const void* ae2  = d_in[14];
    const void* b2   = d_in[15];
    const void* Wp   = d_in[16];
    const void* bp   = d_in[17];

    const int N = in_sizes[3];
    const int E = in_sizes[2];
    const int G = out_size;
    const int* src = ei;
    const int* dst = ei + E;

    // Workspace: index/scan arrays first, big bf16 feature buffers last. ~31 MB.
    char* p = (char*)d_ws;
    auto alloc = [&](size_t bytes) -> char* {
        char* r = p;
        p += (bytes + 255) & ~(size_t)255;
        return r;
    };
    int* flag    = (int*)alloc(32);
    float* consts = (float*)alloc(32);
    int* roff    = (int*)alloc((size_t)(N + 1) * 4);
    int* rpos    = (int*)alloc((size_t)N * 4);
    int* bsum    = (int*)alloc(256 * 4);
    int* eids    = (int*)alloc((size_t)E * 4);
    float* pool  = (float*)alloc((size_t)(G * 64 + G) * 4);
    float* cnt   = pool + (size_t)G * 64;
    float* asrc1 = (float*)alloc((size_t)N * 4 * 4);
    float* adst1 = (float*)alloc((size_t)N * 4 * 4);
    float* asrc2 = asrc1;             // alias: asrc1 dead after k_gat1
    float* adst2 = adst1;
    u16* agg1    = (u16*)alloc((size_t)N * 128 * 2);
    u16* h1      = (u16*)alloc((size_t)N * 128 * 2);
    u16* h2      = h1;                // alias: h1 dead after k_gat1
    u16* agg2    = h1 + (size_t)N * 64;

    hipMemsetAsync(rpos, 0, (size_t)N * 4, stream);
    hipMemsetAsync(pool, 0, (size_t)(G * 64 + G) * 4, stream);

    k_detect<<<1, 64, 0, stream>>>((const u32*)x, flag);
    k_consts<<<1, 64, 0, stream>>>(We1, ae1, We2, ae2, flag, consts);
    k_gemm<128, 4><<<512, 256, 0, stream>>>(x, W1, flag, -1, h1, N);
    k_coef1<<<(N * 4 + 255) / 256, 256, 0, stream>>>(h1, as1, ad1, flag, asrc1, adst1, N);

    int NB = (N + 255) / 256;
    k_count<<<(E + 255) / 256, 256, 0, stream>>>(dst, rpos, E, N);
    k_scan1<<<NB, 256, 0, stream>>>(rpos, roff + 1, bsum, N);
    k_scan2<<<1, 256, 0, stream>>>(bsum, NB);
    k_scan3<<<(N + 256) / 256, 256, 0, stream>>>(roff, bsum, N);
    k_copy<<<NB, 256, 0, stream>>>(roff, rpos, N);
    k_scatter<<<(E + 255) / 256, 256, 0, stream>>>(dst, rpos, eids, E, N);

    k_gat1<<<(N * 64 + 255) / 256, 256, 0, stream>>>(h1, asrc1, adst1, eattr, src, roff,
                                                     eids, flag, consts, b1, agg1, N, E);
    k_gemm<64, 2><<<512, 256, 0, stream>>>(agg1, W2, flag, 0 /*agg1 is bf16*/, h2, N);
    k_coef2<<<(N + 255) / 256, 256, 0, stream>>>(h2, as2, ad2, flag, asrc2, adst2, N);
    k_gat2<<<(N * 64 + 255) / 256, 256, 0, stream>>>(h2, asrc2, adst2, eattr, src, roff,
                                                     eids, flag, consts, b2, agg2, N, E);
    k_pool<<<(((N + 7) / 8) * 64 + 255) / 256, 256, 0, stream>>>(agg2, batch, pool, cnt, N, G);
    k_head<<<1, 64, 0, stream>>>(pool, cnt, Wp, bp, flag, d_out, G);
}